// Round 8
// baseline (123.211 us; speedup 1.0000x reference)
//
#include <hip/hip_runtime.h>
#include <hip/hip_bf16.h>
#include <math.h>

// Shapes: x(8,64,128,128) f32; wt(4,4,64,64,3,3) f32; attn_w(4,64); attn_b(4)
// Subband space: 64x64, 4 subbands, 64 cin, 64 cout.
// feats layout: [b][sub][66][66][64c] bf16, zero border ring (pad=1).

typedef __bf16 bf16x8 __attribute__((ext_vector_type(8)));
typedef float f32x4 __attribute__((ext_vector_type(4)));

__device__ __forceinline__ bf16x8 as_bf16x8(uint4 u) {
    union { uint4 a; bf16x8 b; } c; c.a = u; return c.b;
}
__device__ __forceinline__ unsigned short bf16bits(float f) {
    __hip_bfloat16 h = __float2bfloat16(f);
    union { __hip_bfloat16 h; unsigned short u; } c; c.h = h; return c.u;
}
// async 16B global -> LDS (DMA; LDS dest = wave-uniform base + lane*16)
__device__ __forceinline__ void gload_lds16(const uint4* g, uint4* l) {
    __builtin_amdgcn_global_load_lds(
        (const __attribute__((address_space(1))) unsigned int*)g,
        (__attribute__((address_space(3))) unsigned int*)l, 16, 0, 0);
}

#define FPLANE 34848   // 66*66*8 uint4 per (b,sub) plane
#define FROW   528     // 66*8

// ---------------------------------------------------------------------------
// K1: Haar DWT -> bf16 feats (padded, zero ring) + per-y partial logits
// grid (64 y, 8 b), 256 threads.
// ---------------------------------------------------------------------------
__global__ __launch_bounds__(256)
void dwt_kernel(const float* __restrict__ x, const float* __restrict__ attn_w,
                unsigned short* __restrict__ feats, float* __restrict__ plog) {
    __shared__ uint4 sT[2304];                     // 4 sub * 64 x * 9 chunks (72 bf16)
    __shared__ float sred[64][4];                  // [c][sub]
    unsigned short* sTu = (unsigned short*)sT;
    int y = blockIdx.x, b = blockIdx.y;
    int t = threadIdx.x;
    int c = t >> 2, q = t & 3;

    const float4* r0 = (const float4*)x + ((size_t)(b * 64 + c) * 128 + 2 * y) * 32;
    const float4* r1 = r0 + 32;

    float s0 = 0.f, s1 = 0.f, s2 = 0.f, s3 = 0.f;
    #pragma unroll
    for (int i = 0; i < 8; ++i) {
        int f = i * 4 + q;                         // quad covers 64B contiguous
        float4 p = r0[f], qq = r1[f];
        int xo = 2 * f;
        {
            float a = p.x, bb = p.y, cc = qq.x, dd = qq.y;
            float ll = (a + bb + cc + dd) * 0.5f, h0 = (a + bb - cc - dd) * 0.5f;
            float h1 = (a - bb + cc - dd) * 0.5f, hh = (a - bb - cc + dd) * 0.5f;
            s0 += ll; s1 += h0; s2 += h1; s3 += hh;
            sTu[0 * 4608 + xo * 72 + c] = bf16bits(ll);
            sTu[1 * 4608 + xo * 72 + c] = bf16bits(h0);
            sTu[2 * 4608 + xo * 72 + c] = bf16bits(h1);
            sTu[3 * 4608 + xo * 72 + c] = bf16bits(hh);
        }
        {
            float a = p.z, bb = p.w, cc = qq.z, dd = qq.w;
            float ll = (a + bb + cc + dd) * 0.5f, h0 = (a + bb - cc - dd) * 0.5f;
            float h1 = (a - bb + cc - dd) * 0.5f, hh = (a - bb - cc + dd) * 0.5f;
            s0 += ll; s1 += h0; s2 += h1; s3 += hh;
            sTu[0 * 4608 + (xo + 1) * 72 + c] = bf16bits(ll);
            sTu[1 * 4608 + (xo + 1) * 72 + c] = bf16bits(h0);
            sTu[2 * 4608 + (xo + 1) * 72 + c] = bf16bits(h1);
            sTu[3 * 4608 + (xo + 1) * 72 + c] = bf16bits(hh);
        }
    }
    s0 += __shfl_xor(s0, 1); s0 += __shfl_xor(s0, 2);
    s1 += __shfl_xor(s1, 1); s1 += __shfl_xor(s1, 2);
    s2 += __shfl_xor(s2, 1); s2 += __shfl_xor(s2, 2);
    s3 += __shfl_xor(s3, 1); s3 += __shfl_xor(s3, 2);
    if (q == 0) { sred[c][0] = s0; sred[c][1] = s1; sred[c][2] = s2; sred[c][3] = s3; }
    __syncthreads();
    if (t < 16) {
        int sub = t >> 2, k = t & 3;
        float acc = 0.f;
        #pragma unroll 8
        for (int cc = 0; cc < 64; ++cc)
            acc += attn_w[k * 64 + cc] * sred[cc][sub];
        plog[((size_t)(b * 4 + sub) * 4 + k) * 64 + y] = acc;
    }
    // padded channel-last writes: row y+1 of each plane, zero side borders
    uint4* fpad = (uint4*)feats;
    const uint4 zz = make_uint4(0u, 0u, 0u, 0u);
    for (int e = t; e < 2112; e += 256) {
        int s = e / 528, r = e - s * 528;
        int px = r >> 3, ck = r & 7;
        uint4 v = zz;
        if (px >= 1 && px <= 64) v = sT[s * 576 + (px - 1) * 9 + ck];
        fpad[((size_t)(b * 4 + s) * 66 + (y + 1)) * FROW + r] = v;
    }
    if (y == 0) {
        for (int e = t; e < 2112; e += 256) {
            int s = e / 528, r = e - s * 528;
            fpad[(size_t)(b * 4 + s) * 66 * FROW + r] = zz;
        }
    } else if (y == 63) {
        for (int e = t; e < 2112; e += 256) {
            int s = e / 528, r = e - s * 528;
            fpad[((size_t)(b * 4 + s) * 66 + 65) * FROW + r] = zz;
        }
    }
}

// ---------------------------------------------------------------------------
// K2: attention (from plog) + kernel mixing -> bf16 wmix[b][sub][tap][co][ci]
// grid (64 co, 4 sub), 256 threads.
// ---------------------------------------------------------------------------
__global__ __launch_bounds__(256)
void mix_kernel(const float* __restrict__ wt, const float* __restrict__ attn_b,
                const float* __restrict__ plog, unsigned short* __restrict__ wmix) {
    __shared__ float sLw[4][576];       // [k][ci*9+tap]
    __shared__ float satt[8][4];        // [b][k]
    int co = blockIdx.x, sub = blockIdx.y;
    int t = threadIdx.x;

    if (t < 32) {
        int b = t >> 2, k = t & 3;
        const float* pp = plog + ((size_t)(b * 4 + sub) * 4 + k) * 64;
        float acc = 0.f;
        #pragma unroll 8
        for (int yy = 0; yy < 64; ++yy) acc += pp[yy];
        float logit = acc * (1.0f / 4096.0f) + attn_b[k];
        float m = fmaxf(logit, __shfl_xor(logit, 1));
        m = fmaxf(m, __shfl_xor(m, 2));
        float e = expf(logit - m);
        float s = e + __shfl_xor(e, 1);
        s += __shfl_xor(s, 2);
        satt[b][k] = e / s;
    }
    for (int e = t; e < 2304; e += 256) {
        int k = e / 576, r = e - k * 576;
        sLw[k][r] = wt[((size_t)(k * 4 + sub) * 64 + co) * 576 + r];
    }
    __syncthreads();
    #pragma unroll
    for (int j = 0; j < 18; ++j) {
        int idx = j * 256 + t;
        int b = idx / 576;
        int r = idx - b * 576;
        int tap = r >> 6, ci = r & 63;
        int wi = ci * 9 + tap;
        float v = satt[b][0] * sLw[0][wi] + satt[b][1] * sLw[1][wi]
                + satt[b][2] * sLw[2][wi] + satt[b][3] * sLw[3][wi];
        wmix[((size_t)(b * 4 + sub) * 9 + tap) * 4096 + co * 64 + ci] = bf16bits(v);
    }
}

// ---------------------------------------------------------------------------
// K3: fused MFMA conv (all 4 subbands, sequential staging) + IDWT -> f32 out.
// grid (4 cg, 16 tiles, 8 b) = 512 blocks, 256 threads (4 waves).
// Block: 16x16 px (M=256) x 16 couts x 4 subs; 8 stages of (sub, 32-ci chunk).
// LDS = 20.7K A + 9.2K W = 29.9 KB. launch_bounds(256,3): acc 64 + af 48
// VGPRs need the ~168 cap (bound 4 = 128 would spill, round-5 lesson).
// ---------------------------------------------------------------------------
__global__ __launch_bounds__(256, 3)
void conv_idwt_kernel(const unsigned short* __restrict__ feats,
                      const unsigned short* __restrict__ wmix,
                      float* __restrict__ out) {
    __shared__ uint4 sA[1296];         // [18 py][18 px][4 g] : one sub, 32 ci
    __shared__ uint4 sW[576];          // [9 tap][16 co][4 g] : one sub, 32 ci
    int cg = blockIdx.x;               // 0..3 -> 16 couts
    int tile = blockIdx.y;             // 0..15
    int b = blockIdx.z;
    int y0 = (tile >> 2) * 16, x0 = (tile & 3) * 16;
    int t = threadIdx.x, w = t >> 6, l = t & 63;
    int l16 = l & 15, kg = l >> 4;
    int w4 = w * 4;
    const uint4* fpb  = (const uint4*)feats + (size_t)b * 4 * FPLANE;
    const uint4* wchb = (const uint4*)wmix + (size_t)b * 4 * 4608;

    f32x4 acc[4][4];                   // [sub][r]
    #pragma unroll
    for (int s = 0; s < 4; ++s)
        #pragma unroll
        for (int r = 0; r < 4; ++r)
            acc[s][r] = (f32x4){0.f, 0.f, 0.f, 0.f};

    #pragma unroll
    for (int sub = 0; sub < 4; ++sub) {
        const uint4* fp  = fpb + (size_t)sub * FPLANE;
        const uint4* wch = wchb + (size_t)sub * 4608;
        #pragma unroll
        for (int ck8 = 0; ck8 < 8; ck8 += 4) {   // two 32-ci chunks
            __syncthreads();
            // A halo: padded coords, guard-free async staging
            #pragma unroll
            for (int i = 0; i < 5; ++i) {
                int e = t + i * 256;               // < 1280
                int py = e / 72, rr = e - py * 72, px = rr >> 2, g = rr & 3;
                gload_lds16(fp + (size_t)((y0 + py) * 66 + x0 + px) * 8 + ck8 + g, &sA[e]);
            }
            if (t < 16) {                          // tail e 1280..1295 (py=17)
                int e = 1280 + t;
                int rr = e - 1224, px = rr >> 2, g = rr & 3;
                sA[e] = fp[(size_t)((y0 + 17) * 66 + x0 + px) * 8 + ck8 + g];
            }
            // W: 9 taps x 16 co x 32 ci = 576 slots
            #pragma unroll
            for (int i = 0; i < 2; ++i) {
                int e = t + i * 256;
                int tap = e >> 6, rr = e & 63, co = rr >> 2, g = rr & 3;
                gload_lds16(wch + tap * 512 + (cg * 16 + co) * 8 + ck8 + g, &sW[e]);
            }
            if (t < 64) {                          // tail: wave 0 (uniform branch)
                int e = 512 + t;
                int tap = e >> 6, rr = e & 63, co = rr >> 2, g = rr & 3;
                gload_lds16(wch + tap * 512 + (cg * 16 + co) * 8 + ck8 + g, &sW[e]);
            }
            __syncthreads();
            // sliding-window A-frag cache over dy
            uint4 af[4][3];
            #pragma unroll
            for (int i = 0; i < 4; ++i)
                #pragma unroll
                for (int dx = 0; dx < 3; ++dx)
                    af[i][dx] = sA[((w4 + i) * 18 + l16 + dx) * 4 + kg];
            #pragma unroll
            for (int dy = 0; dy < 3; ++dy) {
                if (dy > 0) {
                    #pragma unroll
                    for (int i = 0; i < 3; ++i)
                        #pragma unroll
                        for (int dx = 0; dx < 3; ++dx)
                            af[i][dx] = af[i + 1][dx];
                    #pragma unroll
                    for (int dx = 0; dx < 3; ++dx)
                        af[3][dx] = sA[((w4 + dy + 3) * 18 + l16 + dx) * 4 + kg];
                }
                #pragma unroll
                for (int dx = 0; dx < 3; ++dx) {
                    bf16x8 bw = as_bf16x8(sW[(dy * 3 + dx) * 64 + l16 * 4 + kg]);
                    #pragma unroll
                    for (int r = 0; r < 4; ++r)
                        acc[sub][r] = __builtin_amdgcn_mfma_f32_16x16x32_bf16(
                            as_bf16x8(af[r][dx]), bw, acc[sub][r], 0, 0, 0);
                }
            }
        }
    }
    // IDWT epilogue: lane holds ll/h0/h1/hh at (ys, xs, co); f32x4 stores.
    int co = cg * 16 + l16;
    #pragma unroll
    for (int r = 0; r < 4; ++r) {
        int ys = y0 + w4 + r;
        float* orow = out + ((size_t)(b * 64 + co) * 128 + 2 * ys) * 128 + 2 * x0 + 8 * kg;
        float av[4], bv[4], cv[4], dv[4];
        #pragma unroll
        for (int j = 0; j < 4; ++j) {
            float ll = acc[0][r][j], h0 = acc[1][r][j];
            float h1 = acc[2][r][j], hh = acc[3][r][j];
            av[j] = (ll + h0 + h1 + hh) * 0.5f;
            bv[j] = (ll + h0 - h1 - hh) * 0.5f;
            cv[j] = (ll - h0 + h1 - hh) * 0.5f;
            dv[j] = (ll - h0 - h1 + hh) * 0.5f;
        }
        *(float4*)(orow)       = make_float4(av[0], bv[0], av[1], bv[1]);
        *(float4*)(orow + 4)   = make_float4(av[2], bv[2], av[3], bv[3]);
        *(float4*)(orow + 128) = make_float4(cv[0], dv[0], cv[1], dv[1]);
        *(float4*)(orow + 132) = make_float4(cv[2], dv[2], cv[3], dv[3]);
    }
}

// ---------------------------------------------------------------------------
extern "C" void kernel_launch(void* const* d_in, const int* in_sizes, int n_in,
                              void* d_out, int out_size, void* d_ws, size_t ws_size,
                              hipStream_t stream) {
    const float* x  = (const float*)d_in[0];
    const float* wt = (const float*)d_in[1];
    const float* aw = (const float*)d_in[2];
    const float* ab = (const float*)d_in[3];
    float* out = (float*)d_out;
    char* ws = (char*)d_ws;

    float* plog           = (float*)ws;                              // 32,768 B
    unsigned short* feats = (unsigned short*)(ws + 32768);           // 17,842,176 B (padded)
    unsigned short* wmix  = (unsigned short*)(ws + 32768 + 17842176); // 2,359,296 B

    hipLaunchKernelGGL(dwt_kernel, dim3(64, 8), dim3(256), 0, stream, x, aw, feats, plog);
    hipLaunchKernelGGL(mix_kernel, dim3(64, 4), dim3(256), 0, stream, wt, ab, plog, wmix);
    hipLaunchKernelGGL(conv_idwt_kernel, dim3(4, 16, 8), dim3(256), 0, stream,
                       feats, wmix, out);
}